// Round 1
// baseline (144.266 us; speedup 1.0000x reference)
//
#include <hip/hip_runtime.h>
#include <stdint.h>

// GradientLoss: sum_c mean( (conv3d_c(x) - conv3d_c(y))^2 ), c in {d,h,w} Sobel dirs.
// conv linear -> conv(x)-conv(y) = conv(x-y). Separable: s=[1,2,1], g=[1,0,-1];
// SAME zero pad; squared output -> flip irrelevant.
//
// R10 = R9 skeleton with TD 16 -> 10 (occupancy fix):
//  - R9 counters: Occupancy 16.7%, VALUBusy 25%, HBM 24% -> latency-bound.
//    Grid was 480 blocks / 256 CUs = 1.875 blocks/CU; LDS (54,272 B) and
//    __launch_bounds__(256,3) allow 3 blocks/CU but the launch never fills them.
//  - TD=10: grid.z = 2*(160/10) = 32 -> 24*32 = 768 blocks = EXACTLY 3/CU,
//    single round, no tail. 12 waves/CU (3/SIMD) to cover the vmcnt(5) DMA
//    latency that 1-2 waves/SIMD could not.
//  - Cost: d-halo 12/10 = 1.2x (was 1.125x) staged traffic; prologue (2 warmup
//    iters) amortized over 12 not 18 iters. Both cheap vs ~1.6x more TLP.
// Kept from R9: exec-masked DMA (lanes 0..55) packing LDS rows to 896 B;
// clamped-index uniform staging (vmcnt(5) every iter, overshoot harmless);
// intra-block 4-wave sharing (XCD-safe dedup).

#define N_  2
#define D_  160
#define H_  192
#define W_  224
#define PS  (H_ * W_)

#define TD  10                 // d-planes computed per block (160/10 = 16 chunks)
#define TH  8                  // h output rows per block (2 per wave)
constexpr int SROWS = TH + 2;  // 10 staged rows per plane
constexpr int ROWF  = 224;     // floats per packed LDS row (= W, 896 B)
constexpr float SCALE = 1.0f / ((float)N_ * D_ * H_ * W_);

#define DMA16(gp, lp) __builtin_amdgcn_global_load_lds(                        \
    (const __attribute__((address_space(1))) void*)(gp),                       \
    (__attribute__((address_space(3))) void*)(lp), 16, 0, 0)

__global__ __launch_bounds__(256, 3)
void grad_loss_kernel(const float* __restrict__ x, const float* __restrict__ y,
                      float* __restrict__ out) {
    __shared__ float sbuf[3][SROWS][2][ROWF];  // 3 bufs x 10 rows x {x,y} x 896B
    __shared__ float wsum[4];

    const int tid  = threadIdx.x;
    const int lane = tid & 63;
    const int wv   = tid >> 6;

    const int h0 = blockIdx.y * TH;
    const int nchunks = D_ / TD;               // 16
    const int nb = blockIdx.z / nchunks;
    const int d0 = (blockIdx.z % nchunks) * TD;

    const float* vbx = x + (size_t)nb * ((size_t)D_ * PS);
    const float* vby = y + (size_t)nb * ((size_t)D_ * PS);

    // ---- 5 wave-uniform staging items per wave: item = (row l, array a) ----
    // DMA dest = wave-uniform base + lane*16; issued under exec mask lane<56,
    // so each row writes exactly bytes [0,896) = 224 floats = W. ✓ packed.
    int sl[5], sa[5], srw[5];
    const float* sb[5];
    #pragma unroll
    for (int k = 0; k < 5; ++k) {
        int item = 5 * wv + k;                 // 20 items over 4 waves
        sl[k] = item >> 1;
        sa[k] = item & 1;
        int ghc = min(max(h0 - 1 + sl[k], 0), H_ - 1);  // clamp; zeroed on read
        srw[k] = ghc * W_;
        sb[k]  = sa[k] ? vby : vbx;
    }
    const int lo4 = lane * 4;                  // source float offset in row

    auto stage = [&](int p, int bsel) {
        int pc = min(max(p, 0), D_ - 1);       // clamp; zeroed via pm on read
        size_t poff = (size_t)pc * PS;
        if (lane < 56) {                       // exec-masked DMA group
            #pragma unroll
            for (int k = 0; k < 5; ++k)
                DMA16(sb[k] + poff + srw[k] + lo4, &sbuf[bsel][sl[k]][sa[k]][0]);
        }
    };

    // ---- compute-side masks ----
    const bool wact = lane < 56;               // 56 lanes x 4 = 224 = W
    float rmask[4];
    #pragma unroll
    for (int r = 0; r < 4; ++r) {              // wave reads staged rows 2wv..2wv+3
        int gh = h0 - 1 + 2 * wv + r;
        rmask[r] = (((unsigned)gh < (unsigned)H_) && wact) ? 1.f : 0.f;
    }
    const int lrd = (lane < 56 ? lane : 55) * 4;  // clamped LDS read offset

    float4 A0[2], A1[2], A2[2], B0[2], B1[2], B2[2];   // d-history (p-2, p-1)
    const float4 z4 = make_float4(0.f, 0.f, 0.f, 0.f);
    #pragma unroll
    for (int j = 0; j < 2; ++j) { A0[j]=A1[j]=A2[j]=B0[j]=B1[j]=B2[j]=z4; }
    float acc = 0.f;

    // ---- prologue: plane d0-1 -> buf0, plane d0 -> buf1 (10 DMAs/wave) ----
    stage(d0 - 1, 0);
    stage(d0,     1);

    for (int it = 0; it < TD + 2; ++it) {
        // oldest 5 outstanding = this iter's plane; keep newest 5 in flight.
        asm volatile("s_waitcnt vmcnt(5)\n\ts_barrier" ::: "memory");

        // uniform staging (exact vmcnt); overshoot iters write buffers that
        // are never read again -> harmless.
        stage(d0 + 1 + it, (it + 2) % 3);

        const int q = d0 - 1 + it;             // plane processed this iter
        const float pm = (q >= 0 && q < D_) ? 1.f : 0.f;
        const int bsel = it % 3;

        // ---- in-plane stencils from LDS (float4 + 2 shuffles per row) ----
        float4 sw[4], gw[4];
        #pragma unroll
        for (int r = 0; r < 4; ++r) {
            const int l = 2 * wv + r;
            const float4 xr = *(const float4*)&sbuf[bsel][l][0][lrd];
            const float4 yr = *(const float4*)&sbuf[bsel][l][1][lrd];
            const float m = rmask[r] * pm;
            float4 v = make_float4((xr.x - yr.x) * m, (xr.y - yr.y) * m,
                                   (xr.z - yr.z) * m, (xr.w - yr.w) * m);
            float Lm = __shfl_up(v.w, 1, 64);
            float Rp = __shfl_down(v.x, 1, 64);
            if (lane == 0) Lm = 0.f;           // w = -1 zero pad
            // lane 55's Rp comes from lane 56: v there is 0 (wact mask) ✓
            sw[r] = make_float4(Lm + 2.f * v.x + v.y,
                                v.x + 2.f * v.y + v.z,
                                v.y + 2.f * v.z + v.w,
                                v.z + 2.f * v.w + Rp);
            gw[r] = make_float4(Lm - v.y, v.x - v.z, v.y - v.w, v.z - Rp);
        }
        float4 n0[2], n1[2], n2[2];
        #pragma unroll
        for (int j = 0; j < 2; ++j) {
            n0[j] = make_float4(sw[j].x + 2.f * sw[j+1].x + sw[j+2].x,
                                sw[j].y + 2.f * sw[j+1].y + sw[j+2].y,
                                sw[j].z + 2.f * sw[j+1].z + sw[j+2].z,
                                sw[j].w + 2.f * sw[j+1].w + sw[j+2].w);  // s_h s_w
            n1[j] = make_float4(sw[j].x - sw[j+2].x, sw[j].y - sw[j+2].y,
                                sw[j].z - sw[j+2].z, sw[j].w - sw[j+2].w); // g_h s_w
            n2[j] = make_float4(gw[j].x + 2.f * gw[j+1].x + gw[j+2].x,
                                gw[j].y + 2.f * gw[j+1].y + gw[j+2].y,
                                gw[j].z + 2.f * gw[j+1].z + gw[j+2].z,
                                gw[j].w + 2.f * gw[j+1].w + gw[j+2].w);  // s_h g_w
        }

        // ---- d-combine for center plane q-1 (A = q-2, B = q-1, n = q) ----
        if (it >= 2 && wact) {
            #pragma unroll
            for (int j = 0; j < 2; ++j) {
                float4 gx = make_float4(A0[j].x - n0[j].x, A0[j].y - n0[j].y,
                                        A0[j].z - n0[j].z, A0[j].w - n0[j].w);
                float4 gy = make_float4(A1[j].x + 2.f * B1[j].x + n1[j].x,
                                        A1[j].y + 2.f * B1[j].y + n1[j].y,
                                        A1[j].z + 2.f * B1[j].z + n1[j].z,
                                        A1[j].w + 2.f * B1[j].w + n1[j].w);
                float4 gz = make_float4(A2[j].x + 2.f * B2[j].x + n2[j].x,
                                        A2[j].y + 2.f * B2[j].y + n2[j].y,
                                        A2[j].z + 2.f * B2[j].z + n2[j].z,
                                        A2[j].w + 2.f * B2[j].w + n2[j].w);
                acc = fmaf(gx.x, gx.x, acc); acc = fmaf(gx.y, gx.y, acc);
                acc = fmaf(gx.z, gx.z, acc); acc = fmaf(gx.w, gx.w, acc);
                acc = fmaf(gy.x, gy.x, acc); acc = fmaf(gy.y, gy.y, acc);
                acc = fmaf(gy.z, gy.z, acc); acc = fmaf(gy.w, gy.w, acc);
                acc = fmaf(gz.x, gz.x, acc); acc = fmaf(gz.y, gz.y, acc);
                acc = fmaf(gz.z, gz.z, acc); acc = fmaf(gz.w, gz.w, acc);
            }
        }

        // ---- rotate history ----
        #pragma unroll
        for (int j = 0; j < 2; ++j) {
            A0[j] = B0[j]; A1[j] = B1[j]; A2[j] = B2[j];
            B0[j] = n0[j]; B1[j] = n1[j]; B2[j] = n2[j];
        }
    }

    asm volatile("s_waitcnt vmcnt(0)" ::: "memory");  // drain before exit

    // ---- reduction: wave butterfly, LDS combine, one atomic per block ----
    #pragma unroll
    for (int off = 32; off > 0; off >>= 1)
        acc += __shfl_xor(acc, off, 64);
    if (lane == 0) wsum[wv] = acc;
    __syncthreads();
    if (tid == 0) {
        float s = (wsum[0] + wsum[1]) + (wsum[2] + wsum[3]);
        atomicAdd(out, s * SCALE);
    }
}

extern "C" void kernel_launch(void* const* d_in, const int* in_sizes, int n_in,
                              void* d_out, int out_size, void* d_ws, size_t ws_size,
                              hipStream_t stream) {
    const float* x = (const float*)d_in[0];
    const float* y = (const float*)d_in[1];
    float* out = (float*)d_out;

    hipMemsetAsync(out, 0, sizeof(float), stream);

    dim3 block(256);                    // 4 waves; one wave = full W x 2 h-rows
    dim3 grid(1,
              H_ / TH,                  // 24
              N_ * (D_ / TD));          // 32  -> 768 blocks = exactly 3/CU
    grad_loss_kernel<<<grid, block, 0, stream>>>(x, y, out);
}

// Round 2
// 137.022 us; speedup vs baseline: 1.0529x; 1.0529x over previous
//
#include <hip/hip_runtime.h>
#include <stdint.h>

// GradientLoss: sum_c mean( (conv3d_c(x) - conv3d_c(y))^2 ), c in {d,h,w} Sobel dirs.
// conv linear -> conv(x)-conv(y) = conv(x-y). Separable: s=[1,2,1], g=[1,0,-1];
// SAME zero pad; squared output -> flip irrelevant.
//
// R11 = R9 skeleton with DEEPER PIPELINE instead of more blocks:
//  - R10 post-mortem: grid=768 (3 blocks/CU nominal) did NOT raise occupancy
//    (16.7 -> 15.1%) and regressed with the halo. Effective residency is capped
//    at ~2 blocks/CU for 54 KB LDS -> TLP via grid is a dead end here.
//  - Latency math: vmcnt(5) waits on a plane staged 2 iters ago; slack ~880 cy
//    vs ~900 cy HBM latency -> every wave stalls. Fix: 4 buffers, 3 planes in
//    flight, vmcnt(10) -> slack = 3 iters ~1300 cy > HBM latency. Each wave is
//    now self-sufficient; DMA streams at throughput, not latency.
//  - LDS 71,680 B -> honest 2 blocks/CU (what we were getting anyway).
//  - TD back to 16: halo 18/16 (undo R10's +10% fetch), grid 480 <= 512
//    resident slots at 2/CU -> single round.
// Kept: exec-masked DMA (lanes 0..55) packing rows to 896 B; clamped-index
// uniform staging (overshoot harmless); intra-block 4-wave sharing.

#define N_  2
#define D_  160
#define H_  192
#define W_  224
#define PS  (H_ * W_)

#define TD  16                 // d-planes computed per block (160/16 = 10 chunks)
#define TH  8                  // h output rows per block (2 per wave)
#define NBUF 4                 // LDS plane buffers (3 planes in flight)
constexpr int SROWS = TH + 2;  // 10 staged rows per plane
constexpr int ROWF  = 224;     // floats per packed LDS row (= W, 896 B)
constexpr float SCALE = 1.0f / ((float)N_ * D_ * H_ * W_);

#define DMA16(gp, lp) __builtin_amdgcn_global_load_lds(                        \
    (const __attribute__((address_space(1))) void*)(gp),                       \
    (__attribute__((address_space(3))) void*)(lp), 16, 0, 0)

__global__ __launch_bounds__(256, 2)
void grad_loss_kernel(const float* __restrict__ x, const float* __restrict__ y,
                      float* __restrict__ out) {
    __shared__ float sbuf[NBUF][SROWS][2][ROWF];  // 4 bufs x 10 rows x {x,y} x 896B
    __shared__ float wsum[4];

    const int tid  = threadIdx.x;
    const int lane = tid & 63;
    const int wv   = tid >> 6;

    const int h0 = blockIdx.y * TH;
    const int nchunks = D_ / TD;               // 10
    const int nb = blockIdx.z / nchunks;
    const int d0 = (blockIdx.z % nchunks) * TD;

    const float* vbx = x + (size_t)nb * ((size_t)D_ * PS);
    const float* vby = y + (size_t)nb * ((size_t)D_ * PS);

    // ---- 5 wave-uniform staging items per wave: item = (row l, array a) ----
    // DMA dest = wave-uniform base + lane*16; issued under exec mask lane<56,
    // so each row writes exactly bytes [0,896) = 224 floats = W. ✓ packed.
    int sl[5], sa[5], srw[5];
    const float* sb[5];
    #pragma unroll
    for (int k = 0; k < 5; ++k) {
        int item = 5 * wv + k;                 // 20 items over 4 waves
        sl[k] = item >> 1;
        sa[k] = item & 1;
        int ghc = min(max(h0 - 1 + sl[k], 0), H_ - 1);  // clamp; zeroed on read
        srw[k] = ghc * W_;
        sb[k]  = sa[k] ? vby : vbx;
    }
    const int lo4 = lane * 4;                  // source float offset in row

    auto stage = [&](int p, int bsel) {
        int pc = min(max(p, 0), D_ - 1);       // clamp; zeroed via pm on read
        size_t poff = (size_t)pc * PS;
        if (lane < 56) {                       // exec-masked DMA group
            #pragma unroll
            for (int k = 0; k < 5; ++k)
                DMA16(sb[k] + poff + srw[k] + lo4, &sbuf[bsel][sl[k]][sa[k]][0]);
        }
    };

    // ---- compute-side masks ----
    const bool wact = lane < 56;               // 56 lanes x 4 = 224 = W
    float rmask[4];
    #pragma unroll
    for (int r = 0; r < 4; ++r) {              // wave reads staged rows 2wv..2wv+3
        int gh = h0 - 1 + 2 * wv + r;
        rmask[r] = (((unsigned)gh < (unsigned)H_) && wact) ? 1.f : 0.f;
    }
    const int lrd = (lane < 56 ? lane : 55) * 4;  // clamped LDS read offset

    float4 A0[2], A1[2], A2[2], B0[2], B1[2], B2[2];   // d-history (p-2, p-1)
    const float4 z4 = make_float4(0.f, 0.f, 0.f, 0.f);
    #pragma unroll
    for (int j = 0; j < 2; ++j) { A0[j]=A1[j]=A2[j]=B0[j]=B1[j]=B2[j]=z4; }
    float acc = 0.f;

    // ---- prologue: 3 planes in flight (15 DMAs/wave outstanding) ----
    stage(d0 - 1, 0);
    stage(d0,     1);
    stage(d0 + 1, 2);

    for (int it = 0; it < TD + 2; ++it) {
        // 15 outstanding; wait until only 10 left -> this iter's 5 are done,
        // 2 newer planes stay in flight.
        asm volatile("s_waitcnt vmcnt(10)\n\ts_barrier" ::: "memory");

        // stage 3 planes ahead into buf (it+3)%4 — the buffer all waves
        // finished reading at iter it-1 (barrier above protects it).
        // Overshoot iters write buffers never read again -> harmless.
        stage(d0 + 2 + it, (it + 3) % NBUF);

        const int q = d0 - 1 + it;             // plane processed this iter
        const float pm = (q >= 0 && q < D_) ? 1.f : 0.f;
        const int bsel = it % NBUF;

        // ---- in-plane stencils from LDS (float4 + 2 shuffles per row) ----
        float4 sw[4], gw[4];
        #pragma unroll
        for (int r = 0; r < 4; ++r) {
            const int l = 2 * wv + r;
            const float4 xr = *(const float4*)&sbuf[bsel][l][0][lrd];
            const float4 yr = *(const float4*)&sbuf[bsel][l][1][lrd];
            const float m = rmask[r] * pm;
            float4 v = make_float4((xr.x - yr.x) * m, (xr.y - yr.y) * m,
                                   (xr.z - yr.z) * m, (xr.w - yr.w) * m);
            float Lm = __shfl_up(v.w, 1, 64);
            float Rp = __shfl_down(v.x, 1, 64);
            if (lane == 0) Lm = 0.f;           // w = -1 zero pad
            // lane 55's Rp comes from lane 56: v there is 0 (wact mask) ✓
            sw[r] = make_float4(Lm + 2.f * v.x + v.y,
                                v.x + 2.f * v.y + v.z,
                                v.y + 2.f * v.z + v.w,
                                v.z + 2.f * v.w + Rp);
            gw[r] = make_float4(Lm - v.y, v.x - v.z, v.y - v.w, v.z - Rp);
        }
        float4 n0[2], n1[2], n2[2];
        #pragma unroll
        for (int j = 0; j < 2; ++j) {
            n0[j] = make_float4(sw[j].x + 2.f * sw[j+1].x + sw[j+2].x,
                                sw[j].y + 2.f * sw[j+1].y + sw[j+2].y,
                                sw[j].z + 2.f * sw[j+1].z + sw[j+2].z,
                                sw[j].w + 2.f * sw[j+1].w + sw[j+2].w);  // s_h s_w
            n1[j] = make_float4(sw[j].x - sw[j+2].x, sw[j].y - sw[j+2].y,
                                sw[j].z - sw[j+2].z, sw[j].w - sw[j+2].w); // g_h s_w
            n2[j] = make_float4(gw[j].x + 2.f * gw[j+1].x + gw[j+2].x,
                                gw[j].y + 2.f * gw[j+1].y + gw[j+2].y,
                                gw[j].z + 2.f * gw[j+1].z + gw[j+2].z,
                                gw[j].w + 2.f * gw[j+1].w + gw[j+2].w);  // s_h g_w
        }

        // ---- d-combine for center plane q-1 (A = q-2, B = q-1, n = q) ----
        if (it >= 2 && wact) {
            #pragma unroll
            for (int j = 0; j < 2; ++j) {
                float4 gx = make_float4(A0[j].x - n0[j].x, A0[j].y - n0[j].y,
                                        A0[j].z - n0[j].z, A0[j].w - n0[j].w);
                float4 gy = make_float4(A1[j].x + 2.f * B1[j].x + n1[j].x,
                                        A1[j].y + 2.f * B1[j].y + n1[j].y,
                                        A1[j].z + 2.f * B1[j].z + n1[j].z,
                                        A1[j].w + 2.f * B1[j].w + n1[j].w);
                float4 gz = make_float4(A2[j].x + 2.f * B2[j].x + n2[j].x,
                                        A2[j].y + 2.f * B2[j].y + n2[j].y,
                                        A2[j].z + 2.f * B2[j].z + n2[j].z,
                                        A2[j].w + 2.f * B2[j].w + n2[j].w);
                acc = fmaf(gx.x, gx.x, acc); acc = fmaf(gx.y, gx.y, acc);
                acc = fmaf(gx.z, gx.z, acc); acc = fmaf(gx.w, gx.w, acc);
                acc = fmaf(gy.x, gy.x, acc); acc = fmaf(gy.y, gy.y, acc);
                acc = fmaf(gy.z, gy.z, acc); acc = fmaf(gy.w, gy.w, acc);
                acc = fmaf(gz.x, gz.x, acc); acc = fmaf(gz.y, gz.y, acc);
                acc = fmaf(gz.z, gz.z, acc); acc = fmaf(gz.w, gz.w, acc);
            }
        }

        // ---- rotate history ----
        #pragma unroll
        for (int j = 0; j < 2; ++j) {
            A0[j] = B0[j]; A1[j] = B1[j]; A2[j] = B2[j];
            B0[j] = n0[j]; B1[j] = n1[j]; B2[j] = n2[j];
        }
    }

    asm volatile("s_waitcnt vmcnt(0)" ::: "memory");  // drain before exit

    // ---- reduction: wave butterfly, LDS combine, one atomic per block ----
    #pragma unroll
    for (int off = 32; off > 0; off >>= 1)
        acc += __shfl_xor(acc, off, 64);
    if (lane == 0) wsum[wv] = acc;
    __syncthreads();
    if (tid == 0) {
        float s = (wsum[0] + wsum[1]) + (wsum[2] + wsum[3]);
        atomicAdd(out, s * SCALE);
    }
}

extern "C" void kernel_launch(void* const* d_in, const int* in_sizes, int n_in,
                              void* d_out, int out_size, void* d_ws, size_t ws_size,
                              hipStream_t stream) {
    const float* x = (const float*)d_in[0];
    const float* y = (const float*)d_in[1];
    float* out = (float*)d_out;

    hipMemsetAsync(out, 0, sizeof(float), stream);

    dim3 block(256);                    // 4 waves; one wave = full W x 2 h-rows
    dim3 grid(1,
              H_ / TH,                  // 24
              N_ * (D_ / TD));          // 20  -> 480 blocks, 2/CU resident
    grad_loss_kernel<<<grid, block, 0, stream>>>(x, y, out);
}